// Round 17
// baseline (134.425 us; speedup 1.0000x reference)
//
#include <hip/hip_runtime.h>
#include <hip/hip_bf16.h>
#include <float.h>
#include <math.h>

#define NN 2048
#define HH 16
#define DDIM 64
#define QB 64   // q-rows per block = 4 waves x 16 rows
#define KB 64
#define KPITCH 144            // K/V LDS row pitch in bytes
#define FPH 66                // fused F LDS pitch in bf16 elements (132B rows)
#define FP 68                 // (fallback kernel) f32 F pitch
#define PARTF 4224            // floats per partial: 64x64 O + 64 m + 64 l
#define NSLOT 4               // max kv-chunk partials per q-tile (32 tiles / 8)
#define NCHUNK 1280           // 16 heads * 80 chunks (CHUNK=8 kv-tiles)
#define WS_PART_OFF 2048      // floats offset: [0]=counter, [512..1536) vmean
#define WS_NEED ((WS_PART_OFF + 32ull * HH * NSLOT * PARTF) * 4ull)

typedef __bf16 bf16x8 __attribute__((ext_vector_type(8)));
typedef __bf16 bf16x4 __attribute__((ext_vector_type(4)));
typedef float f32x4 __attribute__((ext_vector_type(4)));

// Raw barrier: LDS-writes visible; outstanding GLOBAL prefetch loads stay in flight.
__device__ __forceinline__ void barw() {
  __builtin_amdgcn_sched_barrier(0);
  asm volatile("s_waitcnt lgkmcnt(0)" ::: "memory");
  __builtin_amdgcn_s_barrier();
  __builtin_amdgcn_sched_barrier(0);
}

__device__ __forceinline__ unsigned pack2(float a, float b) {
  union { __bf16 h[2]; unsigned u; } x;
  x.h[0] = (__bf16)a; x.h[1] = (__bf16)b;
  return x.u;
}
// unpack u32 holding 2 bf16 -> 2 floats (shift-based, exact)
__device__ __forceinline__ void unpack2(unsigned u, float& lo, float& hi) {
  union { unsigned u; float f; } a, b;
  a.u = u << 16;
  b.u = u & 0xFFFF0000u;
  lo = a.f; hi = b.f;
}

// ============================================================================
// vmean (R17: WIDE): 256 blocks (16 heads x 16 row-chunks of 128 rows) ->
// the 8MB V read uses the whole chip (~2 us) instead of 16 CUs (~20 us of
// serial prelude). wsv zeroed by host-side hipMemsetAsync; /NN moved to
// combine's dead path. atomicAdd per (h,d) — 16K atomics total.
// ============================================================================
__global__ __launch_bounds__(256) void vmean_kernel(
    const float* __restrict__ vg, float* __restrict__ wsv)
{
  __shared__ float red[4][DDIM];
  const int h  = blockIdx.x;      // 0..15
  const int pp = blockIdx.y;      // 0..15: rows pp*128 .. +128
  const int t  = threadIdx.x;
  const int d  = t & 63;
  const int sub = t >> 6;         // 0..3: 32 rows each
  float s = 0.f;
  const float* vp = vg + ((size_t)(h * NN) + pp * 128 + sub * 32) * DDIM + d;
  for (int j = 0; j < 32; ++j) s += vp[(size_t)j * DDIM];
  red[sub][d] = s;
  __syncthreads();
  if (t < DDIM)
    atomicAdd(&wsv[h * DDIM + t], red[0][t] + red[1][t] + red[2][t] + red[3][t]);
}

// ============================================================================
// attend_part (unchanged from R16): coalesced PB, dbuf LDS (1 barrier/tile),
// CHUNK=8 work-steal, bf16 F tile (masked = -inf), ~52.5 KB LDS.
// ============================================================================
__global__ __launch_bounds__(256, 2) void attend_part(
    const float* __restrict__ qg, const float* __restrict__ kg,
    const float* __restrict__ vg, const unsigned int* __restrict__ maskw,
    const float* __restrict__ biasg, const float* __restrict__ prevg,
    float* __restrict__ opart, unsigned int* __restrict__ counter)
{
  __shared__ char   ksh[2][KB * KPITCH]   __attribute__((aligned(16))); // [kv][d] bf16
  __shared__ char   vsh[2][DDIM * KPITCH] __attribute__((aligned(16))); // [d][kv] bf16
  __shared__ __bf16 fsh[2][QB * FPH]      __attribute__((aligned(16))); // fused F, bf16
  __shared__ int chunk_s;

  const int t    = threadIdx.x;
  const int lane = t & 63;
  const int w    = t >> 6;

  // --- mask element-width detection: 4-byte (int/float bool) vs 1-byte ---
  unsigned int mwrd = maskw[t & 255];
  const int mask4 = __syncthreads_and(mwrd == 0u || mwrd == 1u || mwrd == 0x3F800000u);

  const int llo = lane & 15;
  const int lhi = lane >> 4;
  const int cbi  = t & 15;        // K/V staging col group: cb = cbi*4
  const int cb   = cbi << 2;
  const int rgrp = t >> 4;        // K/V staging row group: rows rgrp*4 .. +3

  for (;;) {
    if (t == 0) chunk_s = (int)atomicAdd(counter, 1u);
    __syncthreads();
    const int c = chunk_s;
    if (c >= NCHUNK) break;
    const int h    = c & 15;
    const int rank = c >> 4;

    int qt, ci, len;
    if (rank < 52) {
      int kk = rank;
      qt = 31;
      for (;;) {
        const int nf = (qt + 1) >> 3;
        if (kk < nf) { ci = kk; len = 8; break; }
        kk -= nf; --qt;
      }
    } else {
      const int s = 7 - ((rank - 52) >> 2);
      const int j = (rank - 52) & 3;
      qt  = s + (j << 3) - 1;
      ci  = j;
      len = s;
    }
    const int lo = ci << 3;
    const int hi = lo + len;
    const int qrow0 = qt * QB;
    const int qrow_g = qrow0 + w * 16 + llo;   // this lane's q-row

    // --- Q fragments (B operand), scale 1/8 folded in ---
    bf16x8 aq[2];
    {
      const float* qp = qg + ((size_t)(h * NN + qrow_g)) * DDIM + lhi * 8;
#pragma unroll
      for (int ks = 0; ks < 2; ++ks) {
        float4 f0 = *(const float4*)(qp + ks * 32);
        float4 f1 = *(const float4*)(qp + ks * 32 + 4);
        bf16x8 a;
        a[0] = (__bf16)(f0.x * 0.125f); a[1] = (__bf16)(f0.y * 0.125f);
        a[2] = (__bf16)(f0.z * 0.125f); a[3] = (__bf16)(f0.w * 0.125f);
        a[4] = (__bf16)(f1.x * 0.125f); a[5] = (__bf16)(f1.y * 0.125f);
        a[6] = (__bf16)(f1.z * 0.125f); a[7] = (__bf16)(f1.w * 0.125f);
        aq[ks] = a;
      }
    }

    f32x4 oacc[4];   // O^T frags: oacc[df][r] = O[q=llo-row][d=df*16+lhi*4+r]
#pragma unroll
    for (int i = 0; i < 4; ++i) { f32x4 z = {0.f, 0.f, 0.f, 0.f}; oacc[i] = z; }
    float m_r = -FLT_MAX, l_r = 0.f;

    // ---- prefetch registers ----
    float4 kpre[4], vpre[4];
    float4 pf[4], bfv[4];          // coalesced prev/bias rows
    uint4  mwq[4];                 // mask words (x used for byte path)

    auto issueKV = [&](int kv0) {
#pragma unroll
      for (int e = 0; e < 4; ++e) {
        const int row = (rgrp << 2) + e;
        const size_t gofs = ((size_t)(h * NN + kv0 + row)) * DDIM + cb;
        kpre[e] = *(const float4*)(kg + gofs);
        vpre[e] = *(const float4*)(vg + gofs);
      }
    };
    // coalesced: thread t covers flat float4 f4 = t + e*256 of the 64x64 tile.
    auto issuePBM = [&](int kv0) {
#pragma unroll
      for (int e = 0; e < 4; ++e) {
        const int f4  = t + e * 256;
        const int row = f4 >> 4;
        const int c4  = (f4 & 15) << 2;
        const size_t base = ((size_t)(h * NN) + qrow0 + row) * NN + kv0 + c4;
        pf[e]  = *(const float4*)(prevg + base);
        bfv[e] = *(const float4*)(biasg + base);
        const size_t mb = (size_t)(qrow0 + row) * NN + kv0 + c4;
        if (mask4) mwq[e] = *(const uint4*)(maskw + mb);
        else       mwq[e].x = *(const unsigned int*)((const unsigned char*)maskw + mb);
      }
    };

    issueKV(lo * KB);
    issuePBM(lo * KB);

    for (int tt = lo; tt < hi; ++tt) {
      const int kv0 = tt * KB;
      const int b   = (tt - lo) & 1;
      char*    kshb = ksh[b];
      char*    vshb = vsh[b];
      __bf16*  fshb = fsh[b];
      // ---- stage K [kv][d], V^T [d][kv], fused F (bf16) into buf b ----
#pragma unroll
      for (int e = 0; e < 4; ++e) {
        const int row = (rgrp << 2) + e;
        float4 kf = kpre[e];
        bf16x4 kb4;
        kb4[0] = (__bf16)kf.x; kb4[1] = (__bf16)kf.y;
        kb4[2] = (__bf16)kf.z; kb4[3] = (__bf16)kf.w;
        *(bf16x4*)(kshb + row * KPITCH + (cb << 1)) = kb4;
      }
#pragma unroll
      for (int j = 0; j < 4; ++j) {
        bf16x4 vb4;
        vb4[0] = (__bf16)vpre[0][j]; vb4[1] = (__bf16)vpre[1][j];
        vb4[2] = (__bf16)vpre[2][j]; vb4[3] = (__bf16)vpre[3][j];
        *(bf16x4*)(vshb + (cb + j) * KPITCH + (rgrp << 3)) = vb4;
      }
#pragma unroll
      for (int e = 0; e < 4; ++e) {
        const int f4  = t + e * 256;
        const int row = f4 >> 4;
        const int c4  = (f4 & 15) << 2;
        unsigned mb0, mb1, mb2, mb3;
        if (mask4) { mb0 = mwq[e].x; mb1 = mwq[e].y; mb2 = mwq[e].z; mb3 = mwq[e].w; }
        else {
          mb0 = mwq[e].x & 0xffu; mb1 = (mwq[e].x >> 8) & 0xffu;
          mb2 = (mwq[e].x >> 16) & 0xffu; mb3 = mwq[e].x >> 24;
        }
        const float Fx = mb0 ? (pf[e].x + bfv[e].x) : -INFINITY;
        const float Fy = mb1 ? (pf[e].y + bfv[e].y) : -INFINITY;
        const float Fz = mb2 ? (pf[e].z + bfv[e].z) : -INFINITY;
        const float Fw = mb3 ? (pf[e].w + bfv[e].w) : -INFINITY;
        unsigned* fp = (unsigned*)(fshb + row * FPH + c4);   // 4B-aligned
        fp[0] = pack2(Fx, Fy);
        fp[1] = pack2(Fz, Fw);
      }
      // ---- issue next tile's loads (fly across the barrier) ----
      if (tt + 1 < hi) { issueKV(kv0 + KB); issuePBM(kv0 + KB); }
      barw();   // single barrier per tile: buf b staged by all waves

      // ---- QK^T swapped: S^T[kv][q], each lane: q=llo-row, 16 kv values ----
      f32x4 s[4];
#pragma unroll
      for (int kf = 0; kf < 4; ++kf) { f32x4 z = {0.f, 0.f, 0.f, 0.f}; s[kf] = z; }
#pragma unroll
      for (int ks = 0; ks < 2; ++ks) {
#pragma unroll
        for (int kf = 0; kf < 4; ++kf) {
          const int kvr = kf * 16 + llo;
          bf16x8 ak = *(const bf16x8*)(kshb + kvr * KPITCH + ((ks * 32 + lhi * 8) << 1));
          s[kf] = __builtin_amdgcn_mfma_f32_16x16x32_bf16(ak, aq[ks], s[kf], 0, 0, 0);
        }
      }

      // ---- softmax, in-register; F (bf16) from fused LDS tile ----
      float p[4][4];
      float pmax = -FLT_MAX;
#pragma unroll
      for (int kf = 0; kf < 4; ++kf) {
        const unsigned* fp = (const unsigned*)(fshb + (w * 16 + llo) * FPH + kf * 16 + lhi * 4);
        float fa0, fa1, fa2, fa3;
        unpack2(fp[0], fa0, fa1);
        unpack2(fp[1], fa2, fa3);
        float fa[4] = {fa0, fa1, fa2, fa3};
#pragma unroll
        for (int r = 0; r < 4; ++r) {
          const int j = kv0 + kf * 16 + lhi * 4 + r;
          float sv = s[kf][r] + fa[r];   // masked: -inf + s == -inf
          if (j > qrow_g) sv = -FLT_MAX;
          p[kf][r] = sv;
          pmax = fmaxf(pmax, sv);
        }
      }
      pmax = fmaxf(pmax, __shfl_xor(pmax, 16));
      pmax = fmaxf(pmax, __shfl_xor(pmax, 32));
      const float mnew = fmaxf(m_r, pmax);
      const float resc = __expf(m_r - mnew);   // exp(0)=1 when both -FLT_MAX
      float psum = 0.f;
#pragma unroll
      for (int kf = 0; kf < 4; ++kf)
#pragma unroll
        for (int r = 0; r < 4; ++r) {
          float e = __expf(p[kf][r] - mnew);
          p[kf][r] = e;
          psum += e;
        }
      psum += __shfl_xor(psum, 16);
      psum += __shfl_xor(psum, 32);
      l_r = l_r * resc + psum;
      m_r = mnew;
#pragma unroll
      for (int df = 0; df < 4; ++df) {
        oacc[df][0] *= resc; oacc[df][1] *= resc;
        oacc[df][2] *= resc; oacc[df][3] *= resc;
      }

      // ---- pack P -> bf16; redistribute P^T into PV B-operand; PV MFMAs ----
      unsigned U[4][2];
#pragma unroll
      for (int kf = 0; kf < 4; ++kf) {
        U[kf][0] = pack2(p[kf][0], p[kf][1]);
        U[kf][1] = pack2(p[kf][2], p[kf][3]);
      }
#pragma unroll
      for (int ks = 0; ks < 2; ++ks) {
        unsigned bb[4];
#pragma unroll
        for (int m = 0; m < 4; ++m) {
          const int src = llo + ((((lhi & 1) << 1) + (m >> 1)) << 4);
          const int va = __shfl((int)U[2 * ks + 0][m & 1], src);
          const int vb = __shfl((int)U[2 * ks + 1][m & 1], src);
          bb[m] = (lhi >> 1) ? (unsigned)vb : (unsigned)va;
        }
        union { unsigned u[4]; bf16x8 v; } pb_;
        pb_.u[0] = bb[0]; pb_.u[1] = bb[1]; pb_.u[2] = bb[2]; pb_.u[3] = bb[3];
#pragma unroll
        for (int df = 0; df < 4; ++df) {
          const int dr = df * 16 + llo;
          bf16x8 vf = *(const bf16x8*)(vshb + dr * KPITCH + ((ks * 32 + lhi * 8) << 1));
          oacc[df] = __builtin_amdgcn_mfma_f32_16x16x32_bf16(vf, pb_.v, oacc[df], 0, 0, 0);
        }
      }
      // no second barrier: next tile stages into buf b^1; re-write of buf b
      // (tile tt+2) is ordered after barrier(tt+1) for every wave.
    } // kv tiles

    // ---- write partial (unnormalized O, m, l) ----
    float* pb = opart + (size_t)(((h * 32 + qt) << 2) + ci) * PARTF;
    const int rowl = w * 16 + llo;
#pragma unroll
    for (int df = 0; df < 4; ++df) {
      *(f32x4*)(pb + rowl * 64 + df * 16 + lhi * 4) = oacc[df];
    }
    if (lhi == 0) {
      pb[4096 + rowl] = m_r;
      pb[4160 + rowl] = l_r;
    }
    __syncthreads();   // chunk done; safe to reuse chunk_s/LDS
  } // chunk loop
}

// ============================================================================
// combine: merge up to 4 kv-chunk partials per (qt,h); dead rows -> vmean/NN.
// ============================================================================
__global__ __launch_bounds__(256) void attend_combine(
    const float* __restrict__ opart, const float* __restrict__ wsv,
    float* __restrict__ outg)
{
  const int qt  = blockIdx.x;
  const int h   = blockIdx.y;
  const int t   = threadIdx.x;
  const int nch = (qt + 8) >> 3;   // ceil((qt+1)/8)
  const float* base = opart + (size_t)((h * 32 + qt) << 2) * PARTF;
  const int r  = t >> 2;          // 0..63
  const int c0 = (t & 3) * 16;    // 0,16,32,48

  float m = -FLT_MAX;
  for (int ci = 0; ci < nch; ++ci)
    m = fmaxf(m, base[(size_t)ci * PARTF + 4096 + r]);
  const bool dead = (m == -FLT_MAX);

  float l = 0.f;
  f32x4 a0 = {0,0,0,0}, a1 = {0,0,0,0}, a2 = {0,0,0,0}, a3 = {0,0,0,0};
  for (int ci = 0; ci < nch; ++ci) {
    const float* pb = base + (size_t)ci * PARTF;
    const float wgt = dead ? 0.f : __expf(pb[4096 + r] - m);
    l += pb[4160 + r] * wgt;
    const f32x4 b0 = *(const f32x4*)(pb + r * 64 + c0 + 0);
    const f32x4 b1 = *(const f32x4*)(pb + r * 64 + c0 + 4);
    const f32x4 b2 = *(const f32x4*)(pb + r * 64 + c0 + 8);
    const f32x4 b3 = *(const f32x4*)(pb + r * 64 + c0 + 12);
    a0 += b0 * wgt; a1 += b1 * wgt; a2 += b2 * wgt; a3 += b3 * wgt;
  }

  const float invl = dead ? 0.f : (1.0f / l);
  const float invn = 1.0f / (float)NN;
  float* op = outg + ((size_t)(h * NN) + qt * QB + r) * DDIM + c0;
  const float* vm = wsv + h * DDIM + c0;
#pragma unroll
  for (int i = 0; i < 4; ++i) {
    const f32x4 ai = (i == 0) ? a0 : (i == 1) ? a1 : (i == 2) ? a2 : a3;
    float4 o;
    o.x = dead ? vm[i * 4 + 0] * invn : ai[0] * invl;
    o.y = dead ? vm[i * 4 + 1] * invn : ai[1] * invl;
    o.z = dead ? vm[i * 4 + 2] * invn : ai[2] * invl;
    o.w = dead ? vm[i * 4 + 3] * invn : ai[3] * invl;
    *(float4*)(op + i * 4) = o;
  }
}

// ============================================================================
// Fallback: single-kernel (f32-F version, ws-free).
// ============================================================================
__global__ __launch_bounds__(256, 2) void attend_single(
    const float* __restrict__ qg, const float* __restrict__ kg,
    const float* __restrict__ vg, const unsigned int* __restrict__ maskw,
    const float* __restrict__ biasg, const float* __restrict__ prevg,
    float* __restrict__ outg)
{
  __shared__ char  ksh[KB * KPITCH]   __attribute__((aligned(16)));
  __shared__ char  vsh[DDIM * KPITCH] __attribute__((aligned(16)));
  __shared__ float fsh[QB * FP]       __attribute__((aligned(16)));
  __shared__ float vmean_s[DDIM];

  const int t    = threadIdx.x;
  const int lane = t & 63;
  const int w    = t >> 6;
  const int x    = blockIdx.x;
  const int h    = blockIdx.y;
  const int qt   = (h < 8) ? x : (31 - x);
  const int qrow0 = qt * QB;

  unsigned int mwrd = maskw[t & 255];
  const int mask4 = __syncthreads_and(mwrd == 0u || mwrd == 1u || mwrd == 0x3F800000u);

  const int llo = lane & 15;
  const int lhi = lane >> 4;
  const int cbi  = t & 15;
  const int cb   = cbi << 2;
  const int rgrp = t >> 4;
  const int qrow_g = qrow0 + w * 16 + llo;

  bf16x8 aq[2];
  {
    const float* qp = qg + ((size_t)(h * NN + qrow_g)) * DDIM + lhi * 8;
#pragma unroll
    for (int ks = 0; ks < 2; ++ks) {
      float4 f0 = *(const float4*)(qp + ks * 32);
      float4 f1 = *(const float4*)(qp + ks * 32 + 4);
      bf16x8 a;
      a[0] = (__bf16)(f0.x * 0.125f); a[1] = (__bf16)(f0.y * 0.125f);
      a[2] = (__bf16)(f0.z * 0.125f); a[3] = (__bf16)(f0.w * 0.125f);
      a[4] = (__bf16)(f1.x * 0.125f); a[5] = (__bf16)(f1.y * 0.125f);
      a[6] = (__bf16)(f1.z * 0.125f); a[7] = (__bf16)(f1.w * 0.125f);
      aq[ks] = a;
    }
  }

  f32x4 oacc[4];
#pragma unroll
  for (int i = 0; i < 4; ++i) { f32x4 z = {0.f, 0.f, 0.f, 0.f}; oacc[i] = z; }
  float m_r = -FLT_MAX, l_r = 0.f;

  float4 kpre[4], vpre[4];
  float4 pf[4], bfv[4];
  uint4  mwq[4];

  auto issueKV = [&](int kv0) {
#pragma unroll
    for (int e = 0; e < 4; ++e) {
      const int row = (rgrp << 2) + e;
      const size_t gofs = ((size_t)(h * NN + kv0 + row)) * DDIM + cb;
      kpre[e] = *(const float4*)(kg + gofs);
      vpre[e] = *(const float4*)(vg + gofs);
    }
  };
  auto issuePBM = [&](int kv0) {
#pragma unroll
    for (int e = 0; e < 4; ++e) {
      const int f4  = t + e * 256;
      const int row = f4 >> 4;
      const int c4  = (f4 & 15) << 2;
      const size_t base = ((size_t)(h * NN) + qrow0 + row) * NN + kv0 + c4;
      pf[e]  = *(const float4*)(prevg + base);
      bfv[e] = *(const float4*)(biasg + base);
      const size_t mb = (size_t)(qrow0 + row) * NN + kv0 + c4;
      if (mask4) mwq[e] = *(const uint4*)(maskw + mb);
      else       mwq[e].x = *(const unsigned int*)((const unsigned char*)maskw + mb);
    }
  };

  const int Tq = qt + 1;
  issueKV(0);
  issuePBM(0);

  for (int tt = 0; tt < Tq; ++tt) {
    const int kv0 = tt * KB;
#pragma unroll
    for (int e = 0; e < 4; ++e) {
      const int row = (rgrp << 2) + e;
      float4 kf = kpre[e];
      bf16x4 kb4;
      kb4[0] = (__bf16)kf.x; kb4[1] = (__bf16)kf.y;
      kb4[2] = (__bf16)kf.z; kb4[3] = (__bf16)kf.w;
      *(bf16x4*)(ksh + row * KPITCH + (cb << 1)) = kb4;
    }
#pragma unroll
    for (int j = 0; j < 4; ++j) {
      bf16x4 vb4;
      vb4[0] = (__bf16)vpre[0][j]; vb4[1] = (__bf16)vpre[1][j];
      vb4[2] = (__bf16)vpre[2][j]; vb4[3] = (__bf16)vpre[3][j];
      *(bf16x4*)(vsh + (cb + j) * KPITCH + (rgrp << 3)) = vb4;
    }
#pragma unroll
    for (int e = 0; e < 4; ++e) {
      const int f4  = t + e * 256;
      const int row = f4 >> 4;
      const int c4  = (f4 & 15) << 2;
      unsigned mb0, mb1, mb2, mb3;
      if (mask4) { mb0 = mwq[e].x; mb1 = mwq[e].y; mb2 = mwq[e].z; mb3 = mwq[e].w; }
      else {
        mb0 = mwq[e].x & 0xffu; mb1 = (mwq[e].x >> 8) & 0xffu;
        mb2 = (mwq[e].x >> 16) & 0xffu; mb3 = mwq[e].x >> 24;
      }
      float4 F;
      F.x = mb0 ? (pf[e].x + bfv[e].x) : -FLT_MAX;
      F.y = mb1 ? (pf[e].y + bfv[e].y) : -FLT_MAX;
      F.z = mb2 ? (pf[e].z + bfv[e].z) : -FLT_MAX;
      F.w = mb3 ? (pf[e].w + bfv[e].w) : -FLT_MAX;
      *(float4*)(&fsh[row * FP + c4]) = F;
    }
    if (tt + 1 < Tq) { issueKV(kv0 + KB); issuePBM(kv0 + KB); }
    barw();

    f32x4 s[4];
#pragma unroll
    for (int kf = 0; kf < 4; ++kf) { f32x4 z = {0.f, 0.f, 0.f, 0.f}; s[kf] = z; }
#pragma unroll
    for (int ks = 0; ks < 2; ++ks) {
#pragma unroll
      for (int kf = 0; kf < 4; ++kf) {
        const int kvr = kf * 16 + llo;
        bf16x8 ak = *(const bf16x8*)(ksh + kvr * KPITCH + ((ks * 32 + lhi * 8) << 1));
        s[kf] = __builtin_amdgcn_mfma_f32_16x16x32_bf16(ak, aq[ks], s[kf], 0, 0, 0);
      }
    }

    float p[4][4];
    float pmax = -FLT_MAX;
#pragma unroll
    for (int kf = 0; kf < 4; ++kf) {
      const float4 Fv = *(const float4*)(&fsh[(w * 16 + llo) * FP + kf * 16 + lhi * 4]);
      float fa[4] = {Fv.x, Fv.y, Fv.z, Fv.w};
#pragma unroll
      for (int r = 0; r < 4; ++r) {
        const int j = kv0 + kf * 16 + lhi * 4 + r;
        float sv = s[kf][r] + fa[r];
        if (j > qrow_g) sv = -FLT_MAX;
        p[kf][r] = sv;
        pmax = fmaxf(pmax, sv);
      }
    }
    pmax = fmaxf(pmax, __shfl_xor(pmax, 16));
    pmax = fmaxf(pmax, __shfl_xor(pmax, 32));
    const float mnew = fmaxf(m_r, pmax);
    const float resc = __expf(m_r - mnew);
    float psum = 0.f;
#pragma unroll
    for (int kf = 0; kf < 4; ++kf)
#pragma unroll
      for (int r = 0; r < 4; ++r) {
        float e = __expf(p[kf][r] - mnew);
        p[kf][r] = e;
        psum += e;
      }
    psum += __shfl_xor(psum, 16);
    psum += __shfl_xor(psum, 32);
    l_r = l_r * resc + psum;
    m_r = mnew;
#pragma unroll
    for (int df = 0; df < 4; ++df) {
      oacc[df][0] *= resc; oacc[df][1] *= resc;
      oacc[df][2] *= resc; oacc[df][3] *= resc;
    }

    unsigned U[4][2];
#pragma unroll
    for (int kf = 0; kf < 4; ++kf) {
      U[kf][0] = pack2(p[kf][0], p[kf][1]);
      U[kf][1] = pack2(p[kf][2], p[kf][3]);
    }
#pragma unroll
    for (int ks = 0; ks < 2; ++ks) {
      unsigned bb[4];
#pragma unroll
      for (int m = 0; m < 4; ++m) {
        const int src = llo + ((((lhi & 1) << 1) + (m >> 1)) << 4);
        const int va = __shfl((int)U[2 * ks + 0][m & 1], src);
        const int vb = __shfl((int)U[2 * ks + 1][m & 1], src);
        bb[m] = (lhi >> 1) ? (unsigned)vb : (unsigned)va;
      }
      union { unsigned u[4]; bf16x8 v; } pb_;
      pb_.u[0] = bb[0]; pb_.u[1] = bb[1]; pb_.u[2] = bb[2]; pb_.u[3] = bb[3];
#pragma unroll
      for (int df = 0; df < 4; ++df) {
        const int dr = df * 16 + llo;
        bf16x8 vf = *(const bf16x8*)(vsh + dr * KPITCH + ((ks * 32 + lhi * 8) << 1));
        oacc[df] = __builtin_amdgcn_mfma_f32_16x16x32_bf16(vf, pb_.v, oacc[df], 0, 0, 0);
      }
    }
    barw();
  }

  const int anyNeed = __syncthreads_or(m_r == -FLT_MAX);
  if (anyNeed) {
    if (t < DDIM) vmean_s[t] = 0.f;
    __syncthreads();
    {
      const int d = t & 63, part = t >> 6;
      float sacc = 0.f;
      for (int j = part; j < NN; j += 4) sacc += vg[((size_t)(h * NN + j)) * DDIM + d];
      atomicAdd(&vmean_s[d], sacc);
    }
    __syncthreads();
    if (t < DDIM) vmean_s[t] *= (1.0f / (float)NN);
    __syncthreads();
  }
  const float invl = 1.0f / l_r;
  const bool dead = (m_r == -FLT_MAX);
#pragma unroll
  for (int df = 0; df < 4; ++df) {
    const int dbase = df * 16 + lhi * 4;
    float4 o;
    o.x = dead ? vmean_s[dbase + 0] : oacc[df][0] * invl;
    o.y = dead ? vmean_s[dbase + 1] : oacc[df][1] * invl;
    o.z = dead ? vmean_s[dbase + 2] : oacc[df][2] * invl;
    o.w = dead ? vmean_s[dbase + 3] : oacc[df][3] * invl;
    *(float4*)(outg + ((size_t)(h * NN) + qrow_g) * DDIM + dbase) = o;
  }
}

extern "C" void kernel_launch(void* const* d_in, const int* in_sizes, int n_in,
                              void* d_out, int out_size, void* d_ws, size_t ws_size,
                              hipStream_t stream) {
  (void)in_sizes; (void)n_in; (void)out_size;
  const float* q    = (const float*)d_in[0];
  const float* k    = (const float*)d_in[1];
  const float* v    = (const float*)d_in[2];
  const unsigned int* mask = (const unsigned int*)d_in[3];
  const float* bias = (const float*)d_in[4];
  const float* prev = (const float*)d_in[5];
  float* out = (float*)d_out;

  if (ws_size >= WS_NEED) {
    float* wsf = (float*)d_ws;
    unsigned int* counter = (unsigned int*)wsf;          // [0]
    float* wsv   = wsf + 512;                            // vmean: 16*64 floats
    float* opart = wsf + WS_PART_OFF;                    // partials
    // zero counter + wsv in one small async memset (graph-safe)
    hipMemsetAsync(d_ws, 0, (size_t)(512 + HH * DDIM) * 4, stream);
    vmean_kernel<<<dim3(HH, 16), 256, 0, stream>>>(v, wsv);
    attend_part<<<dim3(1024), 256, 0, stream>>>(q, k, v, mask, bias, prev, opart, counter);
    attend_combine<<<dim3(32, HH), 256, 0, stream>>>(opart, wsv, out);
  } else {
    attend_single<<<dim3(32, HH), 256, 0, stream>>>(q, k, v, mask, bias, prev, out);
  }
}

// Round 18
// 125.360 us; speedup vs baseline: 1.0723x; 1.0723x over previous
//
#include <hip/hip_runtime.h>
#include <hip/hip_bf16.h>
#include <float.h>
#include <math.h>

#define NN 2048
#define HH 16
#define DDIM 64
#define QB 64   // q-rows per block = 4 waves x 16 rows
#define KB 64
#define KPITCH 144            // K/V LDS row pitch in bytes
#define FPH 66                // fused F LDS pitch in bf16 elements (132B rows)
#define FP 68                 // (fallback kernel) f32 F pitch
#define PARTF 4224            // floats per partial: 64x64 O + 64 m + 64 l
#define NSLOT 4               // max kv-chunk partials per q-tile (32 tiles / 8)
#define NCHUNK 1280           // 16 heads * 80 chunks (CHUNK=8 kv-tiles)
#define WS_PART_OFF 2048      // floats offset: [0]=counter, [512..1536) vmean
#define WS_NEED ((WS_PART_OFF + 32ull * HH * NSLOT * PARTF) * 4ull)

typedef __bf16 bf16x8 __attribute__((ext_vector_type(8)));
typedef __bf16 bf16x4 __attribute__((ext_vector_type(4)));
typedef float f32x4 __attribute__((ext_vector_type(4)));

// Raw barrier: LDS-writes visible; outstanding GLOBAL prefetch loads stay in flight.
__device__ __forceinline__ void barw() {
  __builtin_amdgcn_sched_barrier(0);
  asm volatile("s_waitcnt lgkmcnt(0)" ::: "memory");
  __builtin_amdgcn_s_barrier();
  __builtin_amdgcn_sched_barrier(0);
}

__device__ __forceinline__ unsigned pack2(float a, float b) {
  union { __bf16 h[2]; unsigned u; } x;
  x.h[0] = (__bf16)a; x.h[1] = (__bf16)b;
  return x.u;
}
// unpack u32 holding 2 bf16 -> 2 floats (shift-based, exact)
__device__ __forceinline__ void unpack2(unsigned u, float& lo, float& hi) {
  union { unsigned u; float f; } a, b;
  a.u = u << 16;
  b.u = u & 0xFFFF0000u;
  lo = a.f; hi = b.f;
}

// ============================================================================
// vmean (wide): 256 blocks; wsv zeroed by host memset; /NN in combine.
// ============================================================================
__global__ __launch_bounds__(256) void vmean_kernel(
    const float* __restrict__ vg, float* __restrict__ wsv)
{
  __shared__ float red[4][DDIM];
  const int h  = blockIdx.x;      // 0..15
  const int pp = blockIdx.y;      // 0..15: rows pp*128 .. +128
  const int t  = threadIdx.x;
  const int d  = t & 63;
  const int sub = t >> 6;         // 0..3: 32 rows each
  float s = 0.f;
  const float* vp = vg + ((size_t)(h * NN) + pp * 128 + sub * 32) * DDIM + d;
  for (int j = 0; j < 32; ++j) s += vp[(size_t)j * DDIM];
  red[sub][d] = s;
  __syncthreads();
  if (t < DDIM)
    atomicAdd(&wsv[h * DDIM + t], red[0][t] + red[1][t] + red[2][t] + red[3][t]);
}

// ============================================================================
// R18 part: R16 structure + PAIR-INTERLEAVED STEAL ORDER. Consecutive stolen
// chunks = same head, rank pair (2g,2g+1) -> same qt (nf>=2), ADJACENT
// 512-col kv-slices: the pair's two blocks stream the SAME prev/bias DRAM
// rows within ~a tile period -> row-buffer sharing at the memory controller
// (the 256B-per-row-visit granularity is intrinsic to KB=64; this doubles
// requests per open row across blocks instead). Grid 1024 -> 512 (= exact
// resident set, single dispatch wave). Decode: g=c>>5, h=(c&31)>>1,
// rank=(g<<1)|(c&1); rank decode (52 fulls + 28 tails) unchanged.
// ============================================================================
__global__ __launch_bounds__(256, 2) void attend_part(
    const float* __restrict__ qg, const float* __restrict__ kg,
    const float* __restrict__ vg, const unsigned int* __restrict__ maskw,
    const float* __restrict__ biasg, const float* __restrict__ prevg,
    float* __restrict__ opart, unsigned int* __restrict__ counter)
{
  __shared__ char   ksh[2][KB * KPITCH]   __attribute__((aligned(16))); // [kv][d] bf16
  __shared__ char   vsh[2][DDIM * KPITCH] __attribute__((aligned(16))); // [d][kv] bf16
  __shared__ __bf16 fsh[2][QB * FPH]      __attribute__((aligned(16))); // fused F, bf16
  __shared__ int chunk_s;

  const int t    = threadIdx.x;
  const int lane = t & 63;
  const int w    = t >> 6;

  // --- mask element-width detection: 4-byte (int/float bool) vs 1-byte ---
  unsigned int mwrd = maskw[t & 255];
  const int mask4 = __syncthreads_and(mwrd == 0u || mwrd == 1u || mwrd == 0x3F800000u);

  const int llo = lane & 15;
  const int lhi = lane >> 4;
  const int cbi  = t & 15;        // K/V staging col group: cb = cbi*4
  const int cb   = cbi << 2;
  const int rgrp = t >> 4;        // K/V staging row group: rows rgrp*4 .. +3

  for (;;) {
    if (t == 0) chunk_s = (int)atomicAdd(counter, 1u);
    __syncthreads();
    const int c = chunk_s;
    if (c >= NCHUNK) break;
    // pair-interleaved decode: consecutive c -> same head, rank pair
    const int h    = (c & 31) >> 1;
    const int rank = ((c >> 5) << 1) | (c & 1);

    int qt, ci, len;
    if (rank < 52) {
      int kk = rank;
      qt = 31;
      for (;;) {
        const int nf = (qt + 1) >> 3;
        if (kk < nf) { ci = kk; len = 8; break; }
        kk -= nf; --qt;
      }
    } else {
      const int s = 7 - ((rank - 52) >> 2);
      const int j = (rank - 52) & 3;
      qt  = s + (j << 3) - 1;
      ci  = j;
      len = s;
    }
    const int lo = ci << 3;
    const int hi = lo + len;
    const int qrow0 = qt * QB;
    const int qrow_g = qrow0 + w * 16 + llo;   // this lane's q-row

    // --- Q fragments (B operand), scale 1/8 folded in ---
    bf16x8 aq[2];
    {
      const float* qp = qg + ((size_t)(h * NN + qrow_g)) * DDIM + lhi * 8;
#pragma unroll
      for (int ks = 0; ks < 2; ++ks) {
        float4 f0 = *(const float4*)(qp + ks * 32);
        float4 f1 = *(const float4*)(qp + ks * 32 + 4);
        bf16x8 a;
        a[0] = (__bf16)(f0.x * 0.125f); a[1] = (__bf16)(f0.y * 0.125f);
        a[2] = (__bf16)(f0.z * 0.125f); a[3] = (__bf16)(f0.w * 0.125f);
        a[4] = (__bf16)(f1.x * 0.125f); a[5] = (__bf16)(f1.y * 0.125f);
        a[6] = (__bf16)(f1.z * 0.125f); a[7] = (__bf16)(f1.w * 0.125f);
        aq[ks] = a;
      }
    }

    f32x4 oacc[4];   // O^T frags: oacc[df][r] = O[q=llo-row][d=df*16+lhi*4+r]
#pragma unroll
    for (int i = 0; i < 4; ++i) { f32x4 z = {0.f, 0.f, 0.f, 0.f}; oacc[i] = z; }
    float m_r = -FLT_MAX, l_r = 0.f;

    // ---- prefetch registers ----
    float4 kpre[4], vpre[4];
    float4 pf[4], bfv[4];          // coalesced prev/bias rows
    uint4  mwq[4];                 // mask words (x used for byte path)

    auto issueKV = [&](int kv0) {
#pragma unroll
      for (int e = 0; e < 4; ++e) {
        const int row = (rgrp << 2) + e;
        const size_t gofs = ((size_t)(h * NN + kv0 + row)) * DDIM + cb;
        kpre[e] = *(const float4*)(kg + gofs);
        vpre[e] = *(const float4*)(vg + gofs);
      }
    };
    // coalesced: thread t covers flat float4 f4 = t + e*256 of the 64x64 tile.
    auto issuePBM = [&](int kv0) {
#pragma unroll
      for (int e = 0; e < 4; ++e) {
        const int f4  = t + e * 256;
        const int row = f4 >> 4;
        const int c4  = (f4 & 15) << 2;
        const size_t base = ((size_t)(h * NN) + qrow0 + row) * NN + kv0 + c4;
        pf[e]  = *(const float4*)(prevg + base);
        bfv[e] = *(const float4*)(biasg + base);
        const size_t mb = (size_t)(qrow0 + row) * NN + kv0 + c4;
        if (mask4) mwq[e] = *(const uint4*)(maskw + mb);
        else       mwq[e].x = *(const unsigned int*)((const unsigned char*)maskw + mb);
      }
    };

    issueKV(lo * KB);
    issuePBM(lo * KB);

    for (int tt = lo; tt < hi; ++tt) {
      const int kv0 = tt * KB;
      const int b   = (tt - lo) & 1;
      char*    kshb = ksh[b];
      char*    vshb = vsh[b];
      __bf16*  fshb = fsh[b];
      // ---- stage K [kv][d], V^T [d][kv], fused F (bf16) into buf b ----
#pragma unroll
      for (int e = 0; e < 4; ++e) {
        const int row = (rgrp << 2) + e;
        float4 kf = kpre[e];
        bf16x4 kb4;
        kb4[0] = (__bf16)kf.x; kb4[1] = (__bf16)kf.y;
        kb4[2] = (__bf16)kf.z; kb4[3] = (__bf16)kf.w;
        *(bf16x4*)(kshb + row * KPITCH + (cb << 1)) = kb4;
      }
#pragma unroll
      for (int j = 0; j < 4; ++j) {
        bf16x4 vb4;
        vb4[0] = (__bf16)vpre[0][j]; vb4[1] = (__bf16)vpre[1][j];
        vb4[2] = (__bf16)vpre[2][j]; vb4[3] = (__bf16)vpre[3][j];
        *(bf16x4*)(vshb + (cb + j) * KPITCH + (rgrp << 3)) = vb4;
      }
#pragma unroll
      for (int e = 0; e < 4; ++e) {
        const int f4  = t + e * 256;
        const int row = f4 >> 4;
        const int c4  = (f4 & 15) << 2;
        unsigned mb0, mb1, mb2, mb3;
        if (mask4) { mb0 = mwq[e].x; mb1 = mwq[e].y; mb2 = mwq[e].z; mb3 = mwq[e].w; }
        else {
          mb0 = mwq[e].x & 0xffu; mb1 = (mwq[e].x >> 8) & 0xffu;
          mb2 = (mwq[e].x >> 16) & 0xffu; mb3 = mwq[e].x >> 24;
        }
        const float Fx = mb0 ? (pf[e].x + bfv[e].x) : -INFINITY;
        const float Fy = mb1 ? (pf[e].y + bfv[e].y) : -INFINITY;
        const float Fz = mb2 ? (pf[e].z + bfv[e].z) : -INFINITY;
        const float Fw = mb3 ? (pf[e].w + bfv[e].w) : -INFINITY;
        unsigned* fp = (unsigned*)(fshb + row * FPH + c4);   // 4B-aligned
        fp[0] = pack2(Fx, Fy);
        fp[1] = pack2(Fz, Fw);
      }
      // ---- issue next tile's loads (fly across the barrier) ----
      if (tt + 1 < hi) { issueKV(kv0 + KB); issuePBM(kv0 + KB); }
      barw();   // single barrier per tile: buf b staged by all waves

      // ---- QK^T swapped: S^T[kv][q], each lane: q=llo-row, 16 kv values ----
      f32x4 s[4];
#pragma unroll
      for (int kf = 0; kf < 4; ++kf) { f32x4 z = {0.f, 0.f, 0.f, 0.f}; s[kf] = z; }
#pragma unroll
      for (int ks = 0; ks < 2; ++ks) {
#pragma unroll
        for (int kf = 0; kf < 4; ++kf) {
          const int kvr = kf * 16 + llo;
          bf16x8 ak = *(const bf16x8*)(kshb + kvr * KPITCH + ((ks * 32 + lhi * 8) << 1));
          s[kf] = __builtin_amdgcn_mfma_f32_16x16x32_bf16(ak, aq[ks], s[kf], 0, 0, 0);
        }
      }

      // ---- softmax, in-register; F (bf16) from fused LDS tile ----
      float p[4][4];
      float pmax = -FLT_MAX;
#pragma unroll
      for (int kf = 0; kf < 4; ++kf) {
        const unsigned* fp = (const unsigned*)(fshb + (w * 16 + llo) * FPH + kf * 16 + lhi * 4);
        float fa0, fa1, fa2, fa3;
        unpack2(fp[0], fa0, fa1);
        unpack2(fp[1], fa2, fa3);
        float fa[4] = {fa0, fa1, fa2, fa3};
#pragma unroll
        for (int r = 0; r < 4; ++r) {
          const int j = kv0 + kf * 16 + lhi * 4 + r;
          float sv = s[kf][r] + fa[r];   // masked: -inf + s == -inf
          if (j > qrow_g) sv = -FLT_MAX;
          p[kf][r] = sv;
          pmax = fmaxf(pmax, sv);
        }
      }
      pmax = fmaxf(pmax, __shfl_xor(pmax, 16));
      pmax = fmaxf(pmax, __shfl_xor(pmax, 32));
      const float mnew = fmaxf(m_r, pmax);
      const float resc = __expf(m_r - mnew);   // exp(0)=1 when both -FLT_MAX
      float psum = 0.f;
#pragma unroll
      for (int kf = 0; kf < 4; ++kf)
#pragma unroll
        for (int r = 0; r < 4; ++r) {
          float e = __expf(p[kf][r] - mnew);
          p[kf][r] = e;
          psum += e;
        }
      psum += __shfl_xor(psum, 16);
      psum += __shfl_xor(psum, 32);
      l_r = l_r * resc + psum;
      m_r = mnew;
#pragma unroll
      for (int df = 0; df < 4; ++df) {
        oacc[df][0] *= resc; oacc[df][1] *= resc;
        oacc[df][2] *= resc; oacc[df][3] *= resc;
      }

      // ---- pack P -> bf16; redistribute P^T into PV B-operand; PV MFMAs ----
      unsigned U[4][2];
#pragma unroll
      for (int kf = 0; kf < 4; ++kf) {
        U[kf][0] = pack2(p[kf][0], p[kf][1]);
        U[kf][1] = pack2(p[kf][2], p[kf][3]);
      }
#pragma unroll
      for (int ks = 0; ks < 2; ++ks) {
        unsigned bb[4];
#pragma unroll
        for (int m = 0; m < 4; ++m) {
          const int src = llo + ((((lhi & 1) << 1) + (m >> 1)) << 4);
          const int va = __shfl((int)U[2 * ks + 0][m & 1], src);
          const int vb = __shfl((int)U[2 * ks + 1][m & 1], src);
          bb[m] = (lhi >> 1) ? (unsigned)vb : (unsigned)va;
        }
        union { unsigned u[4]; bf16x8 v; } pb_;
        pb_.u[0] = bb[0]; pb_.u[1] = bb[1]; pb_.u[2] = bb[2]; pb_.u[3] = bb[3];
#pragma unroll
        for (int df = 0; df < 4; ++df) {
          const int dr = df * 16 + llo;
          bf16x8 vf = *(const bf16x8*)(vshb + dr * KPITCH + ((ks * 32 + lhi * 8) << 1));
          oacc[df] = __builtin_amdgcn_mfma_f32_16x16x32_bf16(vf, pb_.v, oacc[df], 0, 0, 0);
        }
      }
      // no second barrier: next tile stages into buf b^1; re-write of buf b
      // (tile tt+2) is ordered after barrier(tt+1) for every wave.
    } // kv tiles

    // ---- write partial (unnormalized O, m, l) ----
    float* pb = opart + (size_t)(((h * 32 + qt) << 2) + ci) * PARTF;
    const int rowl = w * 16 + llo;
#pragma unroll
    for (int df = 0; df < 4; ++df) {
      *(f32x4*)(pb + rowl * 64 + df * 16 + lhi * 4) = oacc[df];
    }
    if (lhi == 0) {
      pb[4096 + rowl] = m_r;
      pb[4160 + rowl] = l_r;
    }
    __syncthreads();   // chunk done; safe to reuse chunk_s/LDS
  } // chunk loop
}

// ============================================================================
// combine: merge up to 4 kv-chunk partials per (qt,h); dead rows -> vmean/NN.
// ============================================================================
__global__ __launch_bounds__(256) void attend_combine(
    const float* __restrict__ opart, const float* __restrict__ wsv,
    float* __restrict__ outg)
{
  const int qt  = blockIdx.x;
  const int h   = blockIdx.y;
  const int t   = threadIdx.x;
  const int nch = (qt + 8) >> 3;   // ceil((qt+1)/8)
  const float* base = opart + (size_t)((h * 32 + qt) << 2) * PARTF;
  const int r  = t >> 2;          // 0..63
  const int c0 = (t & 3) * 16;    // 0,16,32,48

  float m = -FLT_MAX;
  for (int ci = 0; ci < nch; ++ci)
    m = fmaxf(m, base[(size_t)ci * PARTF + 4096 + r]);
  const bool dead = (m == -FLT_MAX);

  float l = 0.f;
  f32x4 a0 = {0,0,0,0}, a1 = {0,0,0,0}, a2 = {0,0,0,0}, a3 = {0,0,0,0};
  for (int ci = 0; ci < nch; ++ci) {
    const float* pb = base + (size_t)ci * PARTF;
    const float wgt = dead ? 0.f : __expf(pb[4096 + r] - m);
    l += pb[4160 + r] * wgt;
    const f32x4 b0 = *(const f32x4*)(pb + r * 64 + c0 + 0);
    const f32x4 b1 = *(const f32x4*)(pb + r * 64 + c0 + 4);
    const f32x4 b2 = *(const f32x4*)(pb + r * 64 + c0 + 8);
    const f32x4 b3 = *(const f32x4*)(pb + r * 64 + c0 + 12);
    a0 += b0 * wgt; a1 += b1 * wgt; a2 += b2 * wgt; a3 += b3 * wgt;
  }

  const float invl = dead ? 0.f : (1.0f / l);
  const float invn = 1.0f / (float)NN;
  float* op = outg + ((size_t)(h * NN) + qt * QB + r) * DDIM + c0;
  const float* vm = wsv + h * DDIM + c0;
#pragma unroll
  for (int i = 0; i < 4; ++i) {
    const f32x4 ai = (i == 0) ? a0 : (i == 1) ? a1 : (i == 2) ? a2 : a3;
    float4 o;
    o.x = dead ? vm[i * 4 + 0] * invn : ai[0] * invl;
    o.y = dead ? vm[i * 4 + 1] * invn : ai[1] * invl;
    o.z = dead ? vm[i * 4 + 2] * invn : ai[2] * invl;
    o.w = dead ? vm[i * 4 + 3] * invn : ai[3] * invl;
    *(float4*)(op + i * 4) = o;
  }
}

// ============================================================================
// Fallback: single-kernel (f32-F version, ws-free).
// ============================================================================
__global__ __launch_bounds__(256, 2) void attend_single(
    const float* __restrict__ qg, const float* __restrict__ kg,
    const float* __restrict__ vg, const unsigned int* __restrict__ maskw,
    const float* __restrict__ biasg, const float* __restrict__ prevg,
    float* __restrict__ outg)
{
  __shared__ char  ksh[KB * KPITCH]   __attribute__((aligned(16)));
  __shared__ char  vsh[DDIM * KPITCH] __attribute__((aligned(16)));
  __shared__ float fsh[QB * FP]       __attribute__((aligned(16)));
  __shared__ float vmean_s[DDIM];

  const int t    = threadIdx.x;
  const int lane = t & 63;
  const int w    = t >> 6;
  const int x    = blockIdx.x;
  const int h    = blockIdx.y;
  const int qt   = (h < 8) ? x : (31 - x);
  const int qrow0 = qt * QB;

  unsigned int mwrd = maskw[t & 255];
  const int mask4 = __syncthreads_and(mwrd == 0u || mwrd == 1u || mwrd == 0x3F800000u);

  const int llo = lane & 15;
  const int lhi = lane >> 4;
  const int cbi  = t & 15;
  const int cb   = cbi << 2;
  const int rgrp = t >> 4;
  const int qrow_g = qrow0 + w * 16 + llo;

  bf16x8 aq[2];
  {
    const float* qp = qg + ((size_t)(h * NN + qrow_g)) * DDIM + lhi * 8;
#pragma unroll
    for (int ks = 0; ks < 2; ++ks) {
      float4 f0 = *(const float4*)(qp + ks * 32);
      float4 f1 = *(const float4*)(qp + ks * 32 + 4);
      bf16x8 a;
      a[0] = (__bf16)(f0.x * 0.125f); a[1] = (__bf16)(f0.y * 0.125f);
      a[2] = (__bf16)(f0.z * 0.125f); a[3] = (__bf16)(f0.w * 0.125f);
      a[4] = (__bf16)(f1.x * 0.125f); a[5] = (__bf16)(f1.y * 0.125f);
      a[6] = (__bf16)(f1.z * 0.125f); a[7] = (__bf16)(f1.w * 0.125f);
      aq[ks] = a;
    }
  }

  f32x4 oacc[4];
#pragma unroll
  for (int i = 0; i < 4; ++i) { f32x4 z = {0.f, 0.f, 0.f, 0.f}; oacc[i] = z; }
  float m_r = -FLT_MAX, l_r = 0.f;

  float4 kpre[4], vpre[4];
  float4 pf[4], bfv[4];
  uint4  mwq[4];

  auto issueKV = [&](int kv0) {
#pragma unroll
    for (int e = 0; e < 4; ++e) {
      const int row = (rgrp << 2) + e;
      const size_t gofs = ((size_t)(h * NN + kv0 + row)) * DDIM + cb;
      kpre[e] = *(const float4*)(kg + gofs);
      vpre[e] = *(const float4*)(vg + gofs);
    }
  };
  auto issuePBM = [&](int kv0) {
#pragma unroll
    for (int e = 0; e < 4; ++e) {
      const int f4  = t + e * 256;
      const int row = f4 >> 4;
      const int c4  = (f4 & 15) << 2;
      const size_t base = ((size_t)(h * NN) + qrow0 + row) * NN + kv0 + c4;
      pf[e]  = *(const float4*)(prevg + base);
      bfv[e] = *(const float4*)(biasg + base);
      const size_t mb = (size_t)(qrow0 + row) * NN + kv0 + c4;
      if (mask4) mwq[e] = *(const uint4*)(maskw + mb);
      else       mwq[e].x = *(const unsigned int*)((const unsigned char*)maskw + mb);
    }
  };

  const int Tq = qt + 1;
  issueKV(0);
  issuePBM(0);

  for (int tt = 0; tt < Tq; ++tt) {
    const int kv0 = tt * KB;
#pragma unroll
    for (int e = 0; e < 4; ++e) {
      const int row = (rgrp << 2) + e;
      float4 kf = kpre[e];
      bf16x4 kb4;
      kb4[0] = (__bf16)kf.x; kb4[1] = (__bf16)kf.y;
      kb4[2] = (__bf16)kf.z; kb4[3] = (__bf16)kf.w;
      *(bf16x4*)(ksh + row * KPITCH + (cb << 1)) = kb4;
    }
#pragma unroll
    for (int j = 0; j < 4; ++j) {
      bf16x4 vb4;
      vb4[0] = (__bf16)vpre[0][j]; vb4[1] = (__bf16)vpre[1][j];
      vb4[2] = (__bf16)vpre[2][j]; vb4[3] = (__bf16)vpre[3][j];
      *(bf16x4*)(vsh + (cb + j) * KPITCH + (rgrp << 3)) = vb4;
    }
#pragma unroll
    for (int e = 0; e < 4; ++e) {
      const int f4  = t + e * 256;
      const int row = f4 >> 4;
      const int c4  = (f4 & 15) << 2;
      unsigned mb0, mb1, mb2, mb3;
      if (mask4) { mb0 = mwq[e].x; mb1 = mwq[e].y; mb2 = mwq[e].z; mb3 = mwq[e].w; }
      else {
        mb0 = mwq[e].x & 0xffu; mb1 = (mwq[e].x >> 8) & 0xffu;
        mb2 = (mwq[e].x >> 16) & 0xffu; mb3 = mwq[e].x >> 24;
      }
      float4 F;
      F.x = mb0 ? (pf[e].x + bfv[e].x) : -FLT_MAX;
      F.y = mb1 ? (pf[e].y + bfv[e].y) : -FLT_MAX;
      F.z = mb2 ? (pf[e].z + bfv[e].z) : -FLT_MAX;
      F.w = mb3 ? (pf[e].w + bfv[e].w) : -FLT_MAX;
      *(float4*)(&fsh[row * FP + c4]) = F;
    }
    if (tt + 1 < Tq) { issueKV(kv0 + KB); issuePBM(kv0 + KB); }
    barw();

    f32x4 s[4];
#pragma unroll
    for (int kf = 0; kf < 4; ++kf) { f32x4 z = {0.f, 0.f, 0.f, 0.f}; s[kf] = z; }
#pragma unroll
    for (int ks = 0; ks < 2; ++ks) {
#pragma unroll
      for (int kf = 0; kf < 4; ++kf) {
        const int kvr = kf * 16 + llo;
        bf16x8 ak = *(const bf16x8*)(ksh + kvr * KPITCH + ((ks * 32 + lhi * 8) << 1));
        s[kf] = __builtin_amdgcn_mfma_f32_16x16x32_bf16(ak, aq[ks], s[kf], 0, 0, 0);
      }
    }

    float p[4][4];
    float pmax = -FLT_MAX;
#pragma unroll
    for (int kf = 0; kf < 4; ++kf) {
      const float4 Fv = *(const float4*)(&fsh[(w * 16 + llo) * FP + kf * 16 + lhi * 4]);
      float fa[4] = {Fv.x, Fv.y, Fv.z, Fv.w};
#pragma unroll
      for (int r = 0; r < 4; ++r) {
        const int j = kv0 + kf * 16 + lhi * 4 + r;
        float sv = s[kf][r] + fa[r];
        if (j > qrow_g) sv = -FLT_MAX;
        p[kf][r] = sv;
        pmax = fmaxf(pmax, sv);
      }
    }
    pmax = fmaxf(pmax, __shfl_xor(pmax, 16));
    pmax = fmaxf(pmax, __shfl_xor(pmax, 32));
    const float mnew = fmaxf(m_r, pmax);
    const float resc = __expf(m_r - mnew);
    float psum = 0.f;
#pragma unroll
    for (int kf = 0; kf < 4; ++kf)
#pragma unroll
      for (int r = 0; r < 4; ++r) {
        float e = __expf(p[kf][r] - mnew);
        p[kf][r] = e;
        psum += e;
      }
    psum += __shfl_xor(psum, 16);
    psum += __shfl_xor(psum, 32);
    l_r = l_r * resc + psum;
    m_r = mnew;
#pragma unroll
    for (int df = 0; df < 4; ++df) {
      oacc[df][0] *= resc; oacc[df][1] *= resc;
      oacc[df][2] *= resc; oacc[df][3] *= resc;
    }

    unsigned U[4][2];
#pragma unroll
    for (int kf = 0; kf < 4; ++kf) {
      U[kf][0] = pack2(p[kf][0], p[kf][1]);
      U[kf][1] = pack2(p[kf][2], p[kf][3]);
    }
#pragma unroll
    for (int ks = 0; ks < 2; ++ks) {
      unsigned bb[4];
#pragma unroll
      for (int m = 0; m < 4; ++m) {
        const int src = llo + ((((lhi & 1) << 1) + (m >> 1)) << 4);
        const int va = __shfl((int)U[2 * ks + 0][m & 1], src);
        const int vb = __shfl((int)U[2 * ks + 1][m & 1], src);
        bb[m] = (lhi >> 1) ? (unsigned)vb : (unsigned)va;
      }
      union { unsigned u[4]; bf16x8 v; } pb_;
      pb_.u[0] = bb[0]; pb_.u[1] = bb[1]; pb_.u[2] = bb[2]; pb_.u[3] = bb[3];
#pragma unroll
      for (int df = 0; df < 4; ++df) {
        const int dr = df * 16 + llo;
        bf16x8 vf = *(const bf16x8*)(vsh + dr * KPITCH + ((ks * 32 + lhi * 8) << 1));
        oacc[df] = __builtin_amdgcn_mfma_f32_16x16x32_bf16(vf, pb_.v, oacc[df], 0, 0, 0);
      }
    }
    barw();
  }

  const int anyNeed = __syncthreads_or(m_r == -FLT_MAX);
  if (anyNeed) {
    if (t < DDIM) vmean_s[t] = 0.f;
    __syncthreads();
    {
      const int d = t & 63, part = t >> 6;
      float sacc = 0.f;
      for (int j = part; j < NN; j += 4) sacc += vg[((size_t)(h * NN + j)) * DDIM + d];
      atomicAdd(&vmean_s[d], sacc);
    }
    __syncthreads();
    if (t < DDIM) vmean_s[t] *= (1.0f / (float)NN);
    __syncthreads();
  }
  const float invl = 1.0f / l_r;
  const bool dead = (m_r == -FLT_MAX);
#pragma unroll
  for (int df = 0; df < 4; ++df) {
    const int dbase = df * 16 + lhi * 4;
    float4 o;
    o.x = dead ? vmean_s[dbase + 0] : oacc[df][0] * invl;
    o.y = dead ? vmean_s[dbase + 1] : oacc[df][1] * invl;
    o.z = dead ? vmean_s[dbase + 2] : oacc[df][2] * invl;
    o.w = dead ? vmean_s[dbase + 3] : oacc[df][3] * invl;
    *(float4*)(outg + ((size_t)(h * NN) + qrow_g) * DDIM + dbase) = o;
  }
}

extern "C" void kernel_launch(void* const* d_in, const int* in_sizes, int n_in,
                              void* d_out, int out_size, void* d_ws, size_t ws_size,
                              hipStream_t stream) {
  (void)in_sizes; (void)n_in; (void)out_size;
  const float* q    = (const float*)d_in[0];
  const float* k    = (const float*)d_in[1];
  const float* v    = (const float*)d_in[2];
  const unsigned int* mask = (const unsigned int*)d_in[3];
  const float* bias = (const float*)d_in[4];
  const float* prev = (const float*)d_in[5];
  float* out = (float*)d_out;

  if (ws_size >= WS_NEED) {
    float* wsf = (float*)d_ws;
    unsigned int* counter = (unsigned int*)wsf;          // [0]
    float* wsv   = wsf + 512;                            // vmean: 16*64 floats
    float* opart = wsf + WS_PART_OFF;                    // partials
    hipMemsetAsync(d_ws, 0, (size_t)(512 + HH * DDIM) * 4, stream);
    vmean_kernel<<<dim3(HH, 16), 256, 0, stream>>>(v, wsv);
    attend_part<<<dim3(512), 256, 0, stream>>>(q, k, v, mask, bias, prev, opart, counter);
    attend_combine<<<dim3(32, HH), 256, 0, stream>>>(opart, wsv, out);
  } else {
    attend_single<<<dim3(32, HH), 256, 0, stream>>>(q, k, v, mask, bias, prev, out);
  }
}